// Round 6
// baseline (49.603 us; speedup 1.0000x reference)
//
#include <hip/hip_runtime.h>

// out = -sum_i[ y*log_sigmoid(x) + (1-y)*log_sigmoid(-x) ] / ((1+neg)*pos)
// per-element with z = (label ? x : -x):
//   term = min(z,0) - log1p(exp(-|z|)),  and |z| == |x|
//
// Stage 1: 2048 blocks, each owning a CONTIGUOUS chunk, float4/int4 loads,
//          8x unrolled (16 independent loads in flight), partials -> d_ws.
//          No global atomics (R2: -27us), no device-scope fences (R4: 2x hurt).
// Stage 2: one block reduces the 2048 partials in double and finalizes.

#define NBLOCKS 2048
#define TPB 256

__device__ __forceinline__ void bce_elem(float xv, int lv, float& lsum, int& pcnt)
{
    int p = (lv != 0) ? 1 : 0;
    pcnt += p;
    float ax = fabsf(xv);
    float t  = __expf(-ax);            // in (0,1], no overflow
    float c  = __logf(1.0f + t);       // log1p(exp(-|x|)) >= 0
    float z  = p ? xv : -xv;
    lsum += fminf(z, 0.0f) - c;
}

__global__ __launch_bounds__(TPB, 4) void bce_reduce_kernel(
    const float* __restrict__ x,
    const int* __restrict__ lab,
    float* __restrict__ psum,      // [NBLOCKS] per-block loss partials
    int*   __restrict__ pcount,    // [NBLOCKS] per-block positive counts
    int n)
{
    const int n4 = n >> 2;
    const float4* __restrict__ x4 = reinterpret_cast<const float4*>(x);
    const int4*   __restrict__ l4 = reinterpret_cast<const int4*>(lab);

    // balanced contiguous partition of n4 float4-groups across blocks
    const int chunk = n4 / NBLOCKS;
    const int rem   = n4 % NBLOCKS;
    const int b     = blockIdx.x;
    const int start = b * chunk + (b < rem ? b : rem);
    const int cnt   = chunk + (b < rem ? 1 : 0);
    const int end   = start + cnt;

    float lsum = 0.0f;
    int pcnt = 0;

    int i = start + threadIdx.x;
    // 8x unrolled: 16 independent loads (256B/thread) in flight
    for (; i + 7 * TPB < end; i += 8 * TPB) {
        float4 a0 = x4[i];
        float4 a1 = x4[i + TPB];
        float4 a2 = x4[i + 2 * TPB];
        float4 a3 = x4[i + 3 * TPB];
        float4 a4 = x4[i + 4 * TPB];
        float4 a5 = x4[i + 5 * TPB];
        float4 a6 = x4[i + 6 * TPB];
        float4 a7 = x4[i + 7 * TPB];
        int4   b0 = l4[i];
        int4   b1 = l4[i + TPB];
        int4   b2 = l4[i + 2 * TPB];
        int4   b3 = l4[i + 3 * TPB];
        int4   b4 = l4[i + 4 * TPB];
        int4   b5 = l4[i + 5 * TPB];
        int4   b6 = l4[i + 6 * TPB];
        int4   b7 = l4[i + 7 * TPB];

        bce_elem(a0.x, b0.x, lsum, pcnt); bce_elem(a0.y, b0.y, lsum, pcnt);
        bce_elem(a0.z, b0.z, lsum, pcnt); bce_elem(a0.w, b0.w, lsum, pcnt);
        bce_elem(a1.x, b1.x, lsum, pcnt); bce_elem(a1.y, b1.y, lsum, pcnt);
        bce_elem(a1.z, b1.z, lsum, pcnt); bce_elem(a1.w, b1.w, lsum, pcnt);
        bce_elem(a2.x, b2.x, lsum, pcnt); bce_elem(a2.y, b2.y, lsum, pcnt);
        bce_elem(a2.z, b2.z, lsum, pcnt); bce_elem(a2.w, b2.w, lsum, pcnt);
        bce_elem(a3.x, b3.x, lsum, pcnt); bce_elem(a3.y, b3.y, lsum, pcnt);
        bce_elem(a3.z, b3.z, lsum, pcnt); bce_elem(a3.w, b3.w, lsum, pcnt);
        bce_elem(a4.x, b4.x, lsum, pcnt); bce_elem(a4.y, b4.y, lsum, pcnt);
        bce_elem(a4.z, b4.z, lsum, pcnt); bce_elem(a4.w, b4.w, lsum, pcnt);
        bce_elem(a5.x, b5.x, lsum, pcnt); bce_elem(a5.y, b5.y, lsum, pcnt);
        bce_elem(a5.z, b5.z, lsum, pcnt); bce_elem(a5.w, b5.w, lsum, pcnt);
        bce_elem(a6.x, b6.x, lsum, pcnt); bce_elem(a6.y, b6.y, lsum, pcnt);
        bce_elem(a6.z, b6.z, lsum, pcnt); bce_elem(a6.w, b6.w, lsum, pcnt);
        bce_elem(a7.x, b7.x, lsum, pcnt); bce_elem(a7.y, b7.y, lsum, pcnt);
        bce_elem(a7.z, b7.z, lsum, pcnt); bce_elem(a7.w, b7.w, lsum, pcnt);
    }
    for (; i < end; i += TPB) {
        float4 a = x4[i];
        int4   bb = l4[i];
        bce_elem(a.x, bb.x, lsum, pcnt); bce_elem(a.y, bb.y, lsum, pcnt);
        bce_elem(a.z, bb.z, lsum, pcnt); bce_elem(a.w, bb.w, lsum, pcnt);
    }
    // scalar tail (n not multiple of 4) handled by one thread
    if (b == 0 && threadIdx.x == 0) {
        for (int k = n4 << 2; k < n; ++k)
            bce_elem(x[k], lab[k], lsum, pcnt);
    }

    // wave (64-lane) reduction
#pragma unroll
    for (int off = 32; off > 0; off >>= 1) {
        lsum += __shfl_down(lsum, off);
        pcnt += __shfl_down(pcnt, off);
    }

    // cross-wave reduction via LDS (4 waves)
    __shared__ float wsum[4];
    __shared__ int   wcnt[4];
    int wave = threadIdx.x >> 6;
    int lane = threadIdx.x & 63;
    if (lane == 0) { wsum[wave] = lsum; wcnt[wave] = pcnt; }
    __syncthreads();
    if (threadIdx.x == 0) {
        psum[blockIdx.x]   = wsum[0] + wsum[1] + wsum[2] + wsum[3];
        pcount[blockIdx.x] = wcnt[0] + wcnt[1] + wcnt[2] + wcnt[3];
    }
}

__global__ __launch_bounds__(256) void bce_finalize_kernel(
    const float* __restrict__ psum,
    const int*   __restrict__ pcount,
    float* __restrict__ out, int n, int nparts)
{
    double s = 0.0;
    int    c = 0;
    for (int i = threadIdx.x; i < nparts; i += 256) {
        s += (double)psum[i];
        c += pcount[i];
    }
#pragma unroll
    for (int off = 32; off > 0; off >>= 1) {
        s += __shfl_down(s, off);
        c += __shfl_down(c, off);
    }
    __shared__ double wsd[4];
    __shared__ int    wci[4];
    int wave = threadIdx.x >> 6;
    int lane = threadIdx.x & 63;
    if (lane == 0) { wsd[wave] = s; wci[wave] = c; }
    __syncthreads();
    if (threadIdx.x == 0) {
        double stot = wsd[0] + wsd[1] + wsd[2] + wsd[3];
        double pos  = (double)(wci[0] + wci[1] + wci[2] + wci[3]);
        double neg  = (double)n - pos;
        double scale = -1.0 / ((1.0 + neg) * pos);
        out[0] = (float)(scale * stot);
    }
}

extern "C" void kernel_launch(void* const* d_in, const int* in_sizes, int n_in,
                              void* d_out, int out_size, void* d_ws, size_t ws_size,
                              hipStream_t stream) {
    const float* x   = (const float*)d_in[0];
    const int*   lab = (const int*)d_in[1];
    int n = in_sizes[0];
    float* out = (float*)d_out;

    // ws layout: [0, 8KB) float partial sums, [8KB, 16KB) int partial counts.
    // Every slot is written unconditionally each call -> no memset needed,
    // no state carried across replays.
    float* psum  = (float*)d_ws;
    int*   pcnt  = (int*)((char*)d_ws + NBLOCKS * sizeof(float));

    bce_reduce_kernel<<<NBLOCKS, TPB, 0, stream>>>(x, lab, psum, pcnt, n);
    bce_finalize_kernel<<<1, 256, 0, stream>>>(psum, pcnt, out, n, NBLOCKS);
}